// Round 9
// baseline (32.351 us; speedup 1.0000x reference)
//
#include <hip/hip_runtime.h>
#include <stdint.h>

constexpr int BATCH = 16384;
constexpr int A     = 50;
constexpr int NN    = 51;   // A + 1
constexpr int MAXR  = 16;
constexpr int EPW   = 16;   // elements per wave (4 lanes per element) -> 1024 waves
constexpr int WPB   = 4;    // waves per block

// Fused kernel, EPW=16: phase A = quad-split prefetch-pipelined tree build
// (round-5 lane math x round-8 branchless pipeline); phase B = round-8
// pipelined ring reconstruction, run as two 8-element halves. 1024 waves =
// 1 wave/SIMD: phase-A chip-total issue halves vs EPW=8; phase B issue-neutral.
__global__ __launch_bounds__(WPB * 64, 1)
void fused_kernel(const int* __restrict__ edge, int* __restrict__ out)
{
    const int lane  = threadIdx.x & 63;
    const int wid   = threadIdx.x >> 6;
    const int gbase = (blockIdx.x * WPB + wid) * EPW;  // this wave's first element

    __shared__ uint32_t eds[WPB][EPW][NN];   // packed me[e][n+1][0..3]
    __shared__ uint8_t  tre[WPB][EPW][52];   // Tree bytes; slot 51 = trash
    __shared__ uint8_t  rg [WPB][EPW][104];  // ring_idx pairs; offset 102 = trash

    {   // zero tre + rg (wave-private slices)
        const uint4 z = make_uint4(0, 0, 0, 0);
        uint4* t16 = (uint4*)&tre[wid][0][0];           // 16*52/16 = 52
        if (lane < 52) t16[lane] = z;
        uint4* r16 = (uint4*)&rg[wid][0][0];            // 16*104/16 = 104
        r16[lane] = z;
        r16[lane + 64 < 104 ? lane + 64 : 103] = z;     // cover 64..103 (overlap ok)
    }
    {   // stage + pack this wave's edges: 16 elements x 50 int4, coalesced
        const int4* e4 = (const int4*)edge + (size_t)gbase * A;
        #pragma unroll
        for (int k = 0; k < 13; ++k) {
            const int gi = k * 64 + lane;
            if (gi < EPW * A) {
                const int4 v = e4[gi];
                const int el = gi / A, n = gi - A * el;
                eds[wid][el][n] = (uint32_t)(v.x + 1) | ((uint32_t)(v.y + 1) << 8)
                                | ((uint32_t)(v.z + 1) << 16) | ((uint32_t)(v.w + 1) << 24);
            }
        }
    }
    // (same-wave LDS RAW: hardware lgkmcnt ordering, no barrier needed)

    // ---------------- phase A: tree construction (quad-split) ----------------
    const int e = lane >> 2;    // element within wave
    const int d = lane & 3;     // edge index this lane handles

    uint64_t L = (((uint64_t)1 << NN) - 1) & ~(uint64_t)3;  // lnf: 0,1 found
    uint64_t V = (((uint64_t)1 << NN) - 1) & ~(uint64_t)1;  // nnv: 0 visited
    uint64_t M = 2;               // found & not visited = {1}
    int visiting = 1, nr = 0;
    uint32_t w = eds[wid][e][0];  // prefetched row of node 1

    #pragma unroll 1
    for (int it = 0; it < A; ++it) {
        const int n0 = w & 0xff, n1 = (w >> 8) & 0xff, n2 = (w >> 16) & 0xff, n3 = w >> 24;
        const uint64_t bu = ((uint64_t)1 << n0) | ((uint64_t)1 << n1)
                          | ((uint64_t)1 << n2) | ((uint64_t)1 << n3);
        const int myn = (w >> (8 * d)) & 0xff;
        const uint64_t bm = (uint64_t)1 << myn;
        // --- next-visit precompute + prefetch (overlaps bookkeeping) ---
        const uint64_t visbit = (uint64_t)1 << visiting;
        const uint64_t Mn = (M | (V & bu)) & ~visbit;   // next found&!visited set
        const bool dn = (Mn == 0);
        const uint64_t Msafe = dn ? (uint64_t)2 : Mn;
        const int nv = (int)__builtin_ctzll(Msafe);     // next visiting (dummy 1 if done)
        const uint32_t wn = eds[wid][e][nv - 1];        // prefetch next edge row
        // --- bookkeeping with OLD L,V ---
        const bool dup = ((d > 0) & (myn == n0)) | ((d > 1) & (myn == n1)) | ((d > 2) & (myn == n2));
        const bool fa  = ((L & bm) == 0) | dup;         // found at my edge's turn
        const bool cf  = fa & ((V & bm) != 0) & (myn != 0);   // cycle edge
        const uint64_t Bc = __ballot(cf);               // all 4 lanes of each quad
        const uint32_t qb = (uint32_t)(Bc >> (lane & 60)) & 0xfu;  // my quad's bits
        const int slot = nr + __builtin_popcount(qb & ((1u << d) - 1));
        nr += __builtin_popcount(qb);
        // each lane: Tree set-once + ring slot push (trash-addressed when off)
        tre[wid][e][fa ? 51 : myn] = (uint8_t)visiting;
        *(uint16_t*)&rg[wid][e][(cf & (slot < NN)) ? 2 * slot : 102] =
            (uint16_t)(visiting | (myn << 8));
        L &= ~bu;
        V &= ~visbit;
        M = Mn; visiting = nv;
        w = dn ? 0u : wn;   // done lanes idle harmlessly
        if (__ballot(!dn) == 0) break;
    }

    // ---------------- phase B: rings, two 8-element halves ----------------
    int*  otree = out;                                   // (B,51)
    int2* oridx = (int2*)(out + (size_t)BATCH * NN);     // (B,51) of int2

    #pragma unroll
    for (int h = 0; h < 2; ++h) {
        const int ebase = h * 8;

        uint64_t MkE[8];
        int gE[8], r01E[8];
        #pragma unroll
        for (int j = 0; j < 8; ++j) {
            const int e2 = ebase + j;
            const int b = gbase + e2;
            const int f = (lane < NN) ? (int)tre[wid][e2][lane] : 0;
            const uint32_t pv = (lane < NN) ? *(const uint16_t*)&rg[wid][e2][2 * lane] : 0;
            MkE[j] = ((uint64_t)1 << lane) | ((uint64_t)1 << f);
            gE[j]  = f;
            r01E[j] = (int)pv;                           // slot lane: r0 | r1<<8
            if (lane < NN) {
                otree[(size_t)b * NN + lane] = f;
                oridx[(size_t)b * NN + lane] = make_int2((int)(pv & 0xff), (int)(pv >> 8));
            }
        }
        // 8-way interleaved ancestor-mask doubling
        #pragma unroll
        for (int j6 = 0; j6 < 6; ++j6) {
            #pragma unroll
            for (int j = 0; j < 8; ++j) {
                const int ad = gE[j] << 2;
                const int lo = __builtin_amdgcn_ds_bpermute(ad, (int)(uint32_t)MkE[j]);
                const int hh = __builtin_amdgcn_ds_bpermute(ad, (int)(MkE[j] >> 32));
                MkE[j] |= ((uint64_t)(uint32_t)hh << 32) | (uint32_t)lo;
                if (j6 < 5) gE[j] = __builtin_amdgcn_ds_bpermute(ad, gE[j]);
            }
        }
        // hoisted slot prep (32 independent bpermutes in flight)
        int depE[8], nactE[8], packE[8];
        int s0loE[8], s0hiE[8], s1loE[8], s1hiE[8];
        #pragma unroll
        for (int j = 0; j < 8; ++j) {
            const uint64_t Mk = MkE[j];
            depE[j] = __builtin_popcountll(Mk) - 1;
            const int Mlo = (int)(uint32_t)Mk, Mhi = (int)(Mk >> 32);
            const int r0 = r01E[j] & 0xff, r1 = (r01E[j] >> 8) & 0xff;
            const int a0 = r0 << 2, a1 = r1 << 2;
            const uint64_t set0 = ((uint64_t)(uint32_t)__builtin_amdgcn_ds_bpermute(a0, Mhi) << 32)
                                |  (uint32_t)__builtin_amdgcn_ds_bpermute(a0, Mlo);
            const uint64_t set1 = ((uint64_t)(uint32_t)__builtin_amdgcn_ds_bpermute(a1, Mhi) << 32)
                                |  (uint32_t)__builtin_amdgcn_ds_bpermute(a1, Mlo);
            const int dm  = __builtin_popcountll(set0 & set1) - 1;  // LCA depth
            const int ds0 = __builtin_popcountll(set0) - 1;
            const int ds1 = __builtin_popcountll(set1) - 1;
            s0loE[j] = (int)(uint32_t)set0;  s0hiE[j] = (int)(set0 >> 32);
            s1loE[j] = (int)(uint32_t)set1;  s1hiE[j] = (int)(set1 >> 32);
            packE[j] = dm | (ds0 << 8) | (ds1 << 16);               // all < 64
            nactE[j] = __popcll(__ballot((lane < MAXR) && (r0 != 0)));
        }

        // row emission, 2 rows per iteration
        #pragma unroll
        for (int j = 0; j < 8; ++j) {
            const int b = gbase + ebase + j;
            int* orings = out + (size_t)BATCH * NN * 3 + (size_t)b * (MAXR * A);
            const int nact = nactE[j];
            const int dep  = depE[j];

            int i = 0;
            for (; i + 1 < nact; i += 2) {
                // ---- row i ----
                const uint64_t s0a = ((uint64_t)(uint32_t)__builtin_amdgcn_readlane(s0hiE[j], i) << 32)
                                   |  (uint32_t)__builtin_amdgcn_readlane(s0loE[j], i);
                const uint64_t s1a = ((uint64_t)(uint32_t)__builtin_amdgcn_readlane(s1hiE[j], i) << 32)
                                   |  (uint32_t)__builtin_amdgcn_readlane(s1loE[j], i);
                const int pka = __builtin_amdgcn_readlane(packE[j], i);
                const int s0va = __builtin_amdgcn_readlane(r01E[j], i) & 0xff;
                const int dma = pka & 0xff, ds0a = (pka >> 8) & 0xff, ds1a = (pka >> 16) & 0xff;
                const int ta = ds1a - dma, tua = ta + ds0a - dma;
                const bool on1a = ((s1a >> lane) & 1) && (dep >= dma);
                const bool on0a = ((s0a >> lane) & 1) && (dep >  dma);
                int posa = on1a ? (ds1a - dep) : on0a ? (ta + 1 + ds0a - dep) : 63;
                posa = posa < 63 ? posa : 63;
                // ---- row i+1 ----
                const uint64_t s0b = ((uint64_t)(uint32_t)__builtin_amdgcn_readlane(s0hiE[j], i + 1) << 32)
                                   |  (uint32_t)__builtin_amdgcn_readlane(s0loE[j], i + 1);
                const uint64_t s1b = ((uint64_t)(uint32_t)__builtin_amdgcn_readlane(s1hiE[j], i + 1) << 32)
                                   |  (uint32_t)__builtin_amdgcn_readlane(s1loE[j], i + 1);
                const int pkb = __builtin_amdgcn_readlane(packE[j], i + 1);
                const int s0vb = __builtin_amdgcn_readlane(r01E[j], i + 1) & 0xff;
                const int dmb = pkb & 0xff, ds0b = (pkb >> 8) & 0xff, ds1b = (pkb >> 16) & 0xff;
                const int tb = ds1b - dmb, tub = tb + ds0b - dmb;
                const bool on1b = ((s1b >> lane) & 1) && (dep >= dmb);
                const bool on0b = ((s0b >> lane) & 1) && (dep >  dmb);
                int posb = on1b ? (ds1b - dep) : on0b ? (tb + 1 + ds0b - dep) : 63;
                posb = posb < 63 ? posb : 63;
                // two independent scatters issue back-to-back
                const int pma = __builtin_amdgcn_ds_permute(posa << 2, lane);
                const int pmb = __builtin_amdgcn_ds_permute(posb << 2, lane);
                const int rva = (lane == ta + 1) ? s0va : (lane <= tua ? pma : 0);
                const int rvb = (lane == tb + 1) ? s0vb : (lane <= tub ? pmb : 0);
                if (lane < A) {
                    orings[i * A + lane]       = rva - 1;
                    orings[(i + 1) * A + lane] = rvb - 1;
                }
            }
            if (i < nact) {  // odd tail row
                const uint64_t s0a = ((uint64_t)(uint32_t)__builtin_amdgcn_readlane(s0hiE[j], i) << 32)
                                   |  (uint32_t)__builtin_amdgcn_readlane(s0loE[j], i);
                const uint64_t s1a = ((uint64_t)(uint32_t)__builtin_amdgcn_readlane(s1hiE[j], i) << 32)
                                   |  (uint32_t)__builtin_amdgcn_readlane(s1loE[j], i);
                const int pka = __builtin_amdgcn_readlane(packE[j], i);
                const int s0va = __builtin_amdgcn_readlane(r01E[j], i) & 0xff;
                const int dma = pka & 0xff, ds0a = (pka >> 8) & 0xff, ds1a = (pka >> 16) & 0xff;
                const int ta = ds1a - dma, tua = ta + ds0a - dma;
                const bool on1a = ((s1a >> lane) & 1) && (dep >= dma);
                const bool on0a = ((s0a >> lane) & 1) && (dep >  dma);
                int posa = on1a ? (ds1a - dep) : on0a ? (ta + 1 + ds0a - dep) : 63;
                posa = posa < 63 ? posa : 63;
                const int pma = __builtin_amdgcn_ds_permute(posa << 2, lane);
                const int rva = (lane == ta + 1) ? s0va : (lane <= tua ? pma : 0);
                if (lane < A) orings[i * A + lane] = rva - 1;
            }
            // tail fill: rows nact..15 are all -1 (contiguous, 8B aligned)
            const int startw = nact * A;
            int2* p2 = (int2*)(orings + startw);
            const int n2 = (MAXR * A - startw) >> 1;
            for (int k = lane; k < n2; k += 64) p2[k] = make_int2(-1, -1);
        }
    }
}

extern "C" void kernel_launch(void* const* d_in, const int* in_sizes, int n_in,
                              void* d_out, int out_size, void* d_ws, size_t ws_size,
                              hipStream_t stream) {
    const int* edge = (const int*)d_in[0];
    int* out = (int*)d_out;
    hipLaunchKernelGGL(fused_kernel, dim3(BATCH / (EPW * WPB)), dim3(WPB * 64), 0, stream,
                       edge, out);
}

// Round 10
// 29.779 us; speedup vs baseline: 1.0863x; 1.0863x over previous
//
#include <hip/hip_runtime.h>
#include <stdint.h>

constexpr int BATCH = 16384;
constexpr int A     = 50;
constexpr int NN    = 51;   // A + 1
constexpr int MAXR  = 16;
constexpr int EPW   = 8;    // elements per wave (8 lanes per element) — empirical optimum
constexpr int WPB   = 4;    // waves per block

// Phase-B row prep: everything up to (but not including) the ds_permute.
__device__ __forceinline__ void prep_row(int lane, int dep,
    int s0lo, int s0hi, int s1lo, int s1hi, int pack, int r01, int i,
    int& pos, int& ta, int& tua, int& s0v)
{
    const uint64_t s0 = ((uint64_t)(uint32_t)__builtin_amdgcn_readlane(s0hi, i) << 32)
                      |  (uint32_t)__builtin_amdgcn_readlane(s0lo, i);
    const uint64_t s1 = ((uint64_t)(uint32_t)__builtin_amdgcn_readlane(s1hi, i) << 32)
                      |  (uint32_t)__builtin_amdgcn_readlane(s1lo, i);
    const int pk = __builtin_amdgcn_readlane(pack, i);
    s0v = __builtin_amdgcn_readlane(r01, i) & 0xff;
    const int dm = pk & 0xff, ds0 = (pk >> 8) & 0xff, ds1 = (pk >> 16) & 0xff;
    ta  = ds1 - dm;
    tua = ta + ds0 - dm;
    const bool on1 = ((s1 >> lane) & 1) && (dep >= dm);
    const bool on0 = ((s0 >> lane) & 1) && (dep >  dm);
    int p = on1 ? (ds1 - dep) : on0 ? (ta + 1 + ds0 - dep) : 63;
    pos = p < 63 ? p : 63;
}

// Fused kernel: phase A = octet-split prefetch-pipelined tree build with
// exec-guarded LDS stores (no trash-address scatter -> no same-address write
// serialization); phase B = ring reconstruction with 8-way interleaved
// doubling, hoisted slot prep, 4-row-batched emission. No __syncthreads.
__global__ __launch_bounds__(WPB * 64)
void fused_kernel(const int* __restrict__ edge, int* __restrict__ out)
{
    const int lane  = threadIdx.x & 63;
    const int wid   = threadIdx.x >> 6;
    const int gbase = (blockIdx.x * WPB + wid) * EPW;  // this wave's first element

    __shared__ uint32_t eds[WPB][EPW][NN];   // packed me[e][n+1][0..3]
    __shared__ uint8_t  tre[WPB][EPW][64];   // Tree bytes (padded row)
    __shared__ uint8_t  rg [WPB][EPW][128];  // ring_idx pairs (padded row)

    {   // zero tre + rg (wave-private slices)
        const uint4 z = make_uint4(0, 0, 0, 0);
        uint4* t16 = (uint4*)&tre[wid][0][0];           // 8*64/16 = 32
        if (lane < 32) t16[lane] = z;
        uint4* r16 = (uint4*)&rg[wid][0][0];            // 8*128/16 = 64
        r16[lane] = z;
    }
    {   // stage + pack this wave's edges: 8 elements x 50 int4, coalesced
        const int4* e4 = (const int4*)edge + (size_t)gbase * A;
        #pragma unroll
        for (int k = 0; k < 7; ++k) {
            const int gi = k * 64 + lane;
            if (gi < EPW * A) {
                const int4 v = e4[gi];
                const int el = gi / A, n = gi - A * el;
                eds[wid][el][n] = (uint32_t)(v.x + 1) | ((uint32_t)(v.y + 1) << 8)
                                | ((uint32_t)(v.z + 1) << 16) | ((uint32_t)(v.w + 1) << 24);
            }
        }
    }
    // (same-wave LDS RAW: hardware lgkmcnt ordering, no barrier needed)

    // ---------------- phase A: tree construction ----------------
    const int  e  = lane >> 3;    // element within wave
    const int  d8 = lane & 7;
    const int  d  = d8 & 3;       // edge index this lane mirrors
    const bool hi = d8 >= 4;      // hi half of octet: does the rg store

    uint64_t L = (((uint64_t)1 << NN) - 1) & ~(uint64_t)3;  // lnf: 0,1 found
    uint64_t V = (((uint64_t)1 << NN) - 1) & ~(uint64_t)1;  // nnv: 0 visited
    uint64_t M = 2;               // found & not visited = {1}
    int visiting = 1, nr = 0;
    uint32_t w = eds[wid][e][0];  // prefetched row of node 1

    #pragma unroll 1
    for (int it = 0; it < A; ++it) {
        const int n0 = w & 0xff, n1 = (w >> 8) & 0xff, n2 = (w >> 16) & 0xff, n3 = w >> 24;
        const uint64_t bu = ((uint64_t)1 << n0) | ((uint64_t)1 << n1)
                          | ((uint64_t)1 << n2) | ((uint64_t)1 << n3);
        const int myn = (w >> (8 * d)) & 0xff;
        const uint64_t bm = (uint64_t)1 << myn;
        // --- next-visit precompute + prefetch (overlaps bookkeeping) ---
        const uint64_t visbit = (uint64_t)1 << visiting;
        const uint64_t Mn = (M | (V & bu)) & ~visbit;   // next found&!visited set
        const bool dn = (Mn == 0);
        const uint64_t Msafe = dn ? (uint64_t)2 : Mn;
        const int nv = (int)__builtin_ctzll(Msafe);     // next visiting (dummy 1 if done)
        const uint32_t wn = eds[wid][e][nv - 1];        // prefetch next edge row
        // --- bookkeeping with OLD L,V ---
        const bool dup = ((d > 0) & (myn == n0)) | ((d > 1) & (myn == n1)) | ((d > 2) & (myn == n2));
        const bool fa  = ((L & bm) == 0) | dup;         // found at my edge's turn
        const bool cf  = fa & ((V & bm) != 0) & (myn != 0);   // cycle edge
        const bool cb  = cf & !hi;                      // ballot only low half
        const uint64_t Bc = __ballot(cb);
        const uint32_t qb = (uint32_t)(Bc >> (lane & 56)) & 0xfu;  // my octet's bits
        const int slot = nr + __builtin_popcount(qb & ((1u << d) - 1));
        nr += __builtin_popcount(qb);
        // exec-guarded stores: few active lanes -> near-zero DS bank conflicts
        if (!fa && !hi) tre[wid][e][myn] = (uint8_t)visiting;          // set-once
        if (cf && hi && slot < NN)
            *(uint16_t*)&rg[wid][e][2 * slot] = (uint16_t)(visiting | (myn << 8));
        L &= ~bu;
        V &= ~visbit;
        M = Mn; visiting = nv;
        w = dn ? 0u : wn;   // done lanes idle harmlessly
        if (__ballot(!dn) == 0) break;
    }

    // ---------------- phase B: rings, pipelined ----------------
    int*  otree = out;                                   // (B,51)
    int2* oridx = (int2*)(out + (size_t)BATCH * NN);     // (B,51) of int2

    uint64_t MkE[EPW];
    int gE[EPW], r01E[EPW];
    #pragma unroll
    for (int e2 = 0; e2 < EPW; ++e2) {
        const int b = gbase + e2;
        const int f = (lane < NN) ? (int)tre[wid][e2][lane] : 0;
        const uint32_t pv = (lane < NN) ? *(const uint16_t*)&rg[wid][e2][2 * lane] : 0;
        MkE[e2] = ((uint64_t)1 << lane) | ((uint64_t)1 << f);
        gE[e2]  = f;
        r01E[e2] = (int)pv;                              // slot lane: r0 | r1<<8
        if (lane < NN) {
            otree[(size_t)b * NN + lane] = f;
            oridx[(size_t)b * NN + lane] = make_int2((int)(pv & 0xff), (int)(pv >> 8));
        }
    }
    // 8-way interleaved ancestor-mask doubling
    #pragma unroll
    for (int j6 = 0; j6 < 6; ++j6) {
        #pragma unroll
        for (int e2 = 0; e2 < EPW; ++e2) {
            const int ad = gE[e2] << 2;
            const int lo = __builtin_amdgcn_ds_bpermute(ad, (int)(uint32_t)MkE[e2]);
            const int hh = __builtin_amdgcn_ds_bpermute(ad, (int)(MkE[e2] >> 32));
            MkE[e2] |= ((uint64_t)(uint32_t)hh << 32) | (uint32_t)lo;
            if (j6 < 5) gE[e2] = __builtin_amdgcn_ds_bpermute(ad, gE[e2]);
        }
    }
    // hoisted slot prep for all 8 elements
    int depE[EPW], nactE[EPW], packE[EPW];
    int s0loE[EPW], s0hiE[EPW], s1loE[EPW], s1hiE[EPW];
    #pragma unroll
    for (int e2 = 0; e2 < EPW; ++e2) {
        const uint64_t Mk = MkE[e2];
        depE[e2] = __builtin_popcountll(Mk) - 1;
        const int Mlo = (int)(uint32_t)Mk, Mhi = (int)(Mk >> 32);
        const int r0 = r01E[e2] & 0xff, r1 = (r01E[e2] >> 8) & 0xff;
        const int a0 = r0 << 2, a1 = r1 << 2;
        const uint64_t set0 = ((uint64_t)(uint32_t)__builtin_amdgcn_ds_bpermute(a0, Mhi) << 32)
                            |  (uint32_t)__builtin_amdgcn_ds_bpermute(a0, Mlo);
        const uint64_t set1 = ((uint64_t)(uint32_t)__builtin_amdgcn_ds_bpermute(a1, Mhi) << 32)
                            |  (uint32_t)__builtin_amdgcn_ds_bpermute(a1, Mlo);
        const int dm  = __builtin_popcountll(set0 & set1) - 1;  // LCA depth
        const int ds0 = __builtin_popcountll(set0) - 1;
        const int ds1 = __builtin_popcountll(set1) - 1;
        s0loE[e2] = (int)(uint32_t)set0;  s0hiE[e2] = (int)(set0 >> 32);
        s1loE[e2] = (int)(uint32_t)set1;  s1hiE[e2] = (int)(set1 >> 32);
        packE[e2] = dm | (ds0 << 8) | (ds1 << 16);               // all < 64
        nactE[e2] = __popcll(__ballot((lane < MAXR) && (r0 != 0)));
    }

    // row emission, 4 rows per iteration (independent ds_permutes overlap)
    #pragma unroll
    for (int j = 0; j < EPW; ++j) {
        const int b = gbase + j;
        int* orings = out + (size_t)BATCH * NN * 3 + (size_t)b * (MAXR * A);
        const int nact = nactE[j];
        const int dep  = depE[j];

        int i = 0;
        for (; i + 3 < nact; i += 4) {
            int p0,t0,u0,v0, p1,t1,u1,v1, p2,t2,u2,v2, p3,t3,u3,v3;
            prep_row(lane, dep, s0loE[j], s0hiE[j], s1loE[j], s1hiE[j], packE[j], r01E[j], i+0, p0,t0,u0,v0);
            prep_row(lane, dep, s0loE[j], s0hiE[j], s1loE[j], s1hiE[j], packE[j], r01E[j], i+1, p1,t1,u1,v1);
            prep_row(lane, dep, s0loE[j], s0hiE[j], s1loE[j], s1hiE[j], packE[j], r01E[j], i+2, p2,t2,u2,v2);
            prep_row(lane, dep, s0loE[j], s0hiE[j], s1loE[j], s1hiE[j], packE[j], r01E[j], i+3, p3,t3,u3,v3);
            const int m0 = __builtin_amdgcn_ds_permute(p0 << 2, lane);
            const int m1 = __builtin_amdgcn_ds_permute(p1 << 2, lane);
            const int m2 = __builtin_amdgcn_ds_permute(p2 << 2, lane);
            const int m3 = __builtin_amdgcn_ds_permute(p3 << 2, lane);
            const int r0v = (lane == t0 + 1) ? v0 : (lane <= u0 ? m0 : 0);
            const int r1v = (lane == t1 + 1) ? v1 : (lane <= u1 ? m1 : 0);
            const int r2v = (lane == t2 + 1) ? v2 : (lane <= u2 ? m2 : 0);
            const int r3v = (lane == t3 + 1) ? v3 : (lane <= u3 ? m3 : 0);
            if (lane < A) {
                orings[(i + 0) * A + lane] = r0v - 1;
                orings[(i + 1) * A + lane] = r1v - 1;
                orings[(i + 2) * A + lane] = r2v - 1;
                orings[(i + 3) * A + lane] = r3v - 1;
            }
        }
        for (; i < nact; ++i) {
            int p0, t0, u0, v0;
            prep_row(lane, dep, s0loE[j], s0hiE[j], s1loE[j], s1hiE[j], packE[j], r01E[j], i, p0,t0,u0,v0);
            const int m0 = __builtin_amdgcn_ds_permute(p0 << 2, lane);
            const int r0v = (lane == t0 + 1) ? v0 : (lane <= u0 ? m0 : 0);
            if (lane < A) orings[i * A + lane] = r0v - 1;
        }
        // tail fill: rows nact..15 are all -1 (contiguous, 8B aligned)
        const int startw = nact * A;
        int2* p2w = (int2*)(orings + startw);
        const int n2 = (MAXR * A - startw) >> 1;
        for (int k = lane; k < n2; k += 64) p2w[k] = make_int2(-1, -1);
    }
}

extern "C" void kernel_launch(void* const* d_in, const int* in_sizes, int n_in,
                              void* d_out, int out_size, void* d_ws, size_t ws_size,
                              hipStream_t stream) {
    const int* edge = (const int*)d_in[0];
    int* out = (int*)d_out;
    hipLaunchKernelGGL(fused_kernel, dim3(BATCH / (EPW * WPB)), dim3(WPB * 64), 0, stream,
                       edge, out);
}